// Round 6
// baseline (3103.527 us; speedup 1.0000x reference)
//
#include <hip/hip_runtime.h>
#include <hip/hip_bf16.h>
#include <math.h>

constexpr int B_ = 4, N_ = 8192, H_ = 8;
constexpr float SQT    = 0.35355339059327373f;   // sqrt(SOFTMAX_TEMP)
constexpr float RFF_S  = 0.17677669529663687f;   // sqrt(2/64)
constexpr float RATIO  = 0.0625f;                // 256^-0.5
constexpr float SM_EPS = 1e-6f;
constexpr float NORM_EPS = 1e-6f;

// pass1 chunking
constexpr int NCH = 64, CHUNK = N_ / NCH;        // 128 rows/block, grid 2048

// ws layout (float offsets)
constexpr int OFF_CONST = 0;        // 64
constexpr int OFF_FLAG  = 63;       // mask dtype flag
constexpr int OFF_MK    = 64;       // 32
constexpr int OFF_NMASK = 96;       // 32
constexpr int OFF_KSUM  = 128;      // 32*256
constexpr int OFF_VSUM  = 8320;     // 32*64
constexpr int OFF_BMAX  = 10368;    // 32*64 = 2048
constexpr int OFF_CTX   = 12416;    // 32*256*64
constexpr int OFF_PROJT = 536704;   // 48*256*4
constexpr int OFF_OWT   = 585856;   // 512*64 -> end 618624
constexpr int ZERO_BEG  = OFF_NMASK;
constexpr int ZERO_END  = OFF_CTX + 32*16384;

__global__ __launch_bounds__(256)
void k_consts(const float* __restrict__ wrpe, const float* __restrict__ proj,
              const float* __restrict__ outw, const unsigned int* __restrict__ maskw,
              float* __restrict__ W) {
  __shared__ float exs[128];
  __shared__ float qwv[8][2];
  __shared__ int f_gt1, f_oddnz, f_evennz;
  int tid = threadIdx.x;
  if (tid == 0) { f_gt1 = 0; f_oddnz = 0; f_evennz = 0; }
  __syncthreads();
  {
    int gt1 = 0, oddnz = 0, evennz = 0;
    for (int i = tid; i < 8192; i += 256) {
      unsigned int v = maskw[i];
      if (v > 1u) gt1 = 1;
      if (v != 0u) { if (i & 1) oddnz = 1; else evennz = 1; }
    }
    if (gt1)    atomicOr(&f_gt1, 1);
    if (oddnz)  atomicOr(&f_oddnz, 1);
    if (evennz) atomicOr(&f_evennz, 1);
  }
  if (tid < 128) {
    int h = tid >> 4, r = (tid >> 3) & 1, c = (tid >> 2) & 1, k = tid & 3;
    float s = 0.f;
    for (int d = 0; d < 64; ++d) s += wrpe[(h*64 + d)*16 + r*8 + c*4 + k];
    exs[tid] = expf(fminf(s, 50.f));
  }
  __syncthreads();
  if (tid == 0) {
    float flag = 0.f;
    if (f_gt1) flag = 1.f;
    else if (!f_oddnz && f_evennz) flag = 2.f;
    W[OFF_FLAG] = flag;
  }
  if (tid < 32) {
    int h = tid >> 2, r = (tid >> 1) & 1, c = tid & 1;
    float s = 0.f;
    for (int k = 0; k < 4; ++k) s += exs[h*16 + r*8 + c*4 + k];
    if (c == 0) W[OFF_CONST + h*8 + 3 + r] = sqrtf(s);   // sqrt(alpha[h][r])
    else        qwv[h][r] = s;
  }
  __syncthreads();
  if (tid < 8) {
    int h = tid;
    float s0 = sqrtf(qwv[h][0]), s1 = sqrtf(qwv[h][1]);
    W[OFF_CONST + h*8 + 0] = s0;   // new_qw = [qw0, qw0, qw1]
    W[OFF_CONST + h*8 + 1] = s0;
    W[OFF_CONST + h*8 + 2] = s1;
  }
  for (int i = tid; i < 32*NCH; i += 256) W[OFF_BMAX + i] = -INFINITY;
  // projT4[(dq*256+f)*4 + j] = proj[f*192 + dq*4 + j]
  for (int i = tid; i < 48*256; i += 256) {
    int dq = i >> 8, f = i & 255;
    float4 v = *(const float4*)&proj[f*192 + dq*4];
    *(float4*)&W[OFF_PROJT + i*4] = v;
  }
  // out_wT[c][j] = out_w[j][c]
  for (int i = tid; i < 512*64; i += 256) {
    int c = i >> 6, j = i & 63;
    W[OFF_OWT + c*64 + j] = outw[j*512 + c];
  }
}

__device__ __forceinline__ int read_mask(const void* maskp, int mtype, size_t idx) {
  if (mtype == 1) return (int)((const unsigned char*)maskp)[idx];
  if (mtype == 2) return (int)((const long long*)maskp)[idx];
  return ((const int*)maskp)[idx];
}

__global__ __launch_bounds__(256, 4)
void k_pass1(const float* __restrict__ key, const float* __restrict__ value,
             const float* __restrict__ coords, const void* __restrict__ maskp,
             const float* __restrict__ omR_g, const float* __restrict__ omA_g,
             float* __restrict__ W) {
  int bh = blockIdx.x / NCH, ch = blockIdx.x % NCH;
  int b = bh >> 3, h = bh & 7;
  int tid = threadIdx.x;
  __shared__ __align__(16) float kc[16][192];
  __shared__ __align__(16) float vt[16][64];
  __shared__ float sxyz[16][3];
  __shared__ float mtile[16];
  __shared__ float diag[16];
  __shared__ float red[16][16];
  __shared__ float omR[64], omA[32];
  __shared__ float mred[256];

  if (tid < 64) omR[tid] = omR_g[tid];
  if (tid < 32) omA[tid] = omA_g[tid];
  int mtype = (int)W[OFF_FLAG];
  float s0 = W[OFF_CONST + h*8 + 0];
  float s1 = W[OFF_CONST + h*8 + 1];
  float s2 = W[OFF_CONST + h*8 + 2];
  float a0 = W[OFF_CONST + h*8 + 3] * RFF_S;
  float a1 = W[OFF_CONST + h*8 + 4] * RFF_S;

  float ctx[64];
  #pragma unroll
  for (int e = 0; e < 64; ++e) ctx[e] = 0.f;
  float ksum_acc = 0.f, maxd = -INFINITY;
  float vs = 0.f, nm = 0.f;

  int r = tid >> 4, l = tid & 15;
  for (int t = 0; t < CHUNK/16; ++t) {
    int n = ch*CHUNK + t*16 + r;
    __syncthreads();
    {
      const float* kp = key + ((size_t)b*N_ + n)*512 + h*64 + l*4;
      float4 kv = *(const float4*)kp;
      kc[r][l*4+0] = kv.x*SQT; kc[r][l*4+1] = kv.y*SQT;
      kc[r][l*4+2] = kv.z*SQT; kc[r][l*4+3] = kv.w*SQT;
      const float* vp = value + ((size_t)b*N_ + n)*512 + h*64 + l*4;
      *(float4*)&vt[r][l*4] = *(const float4*)vp;
      if (l == 0) {
        const float* cp = coords + ((size_t)b*N_ + n)*3;
        sxyz[r][0] = cp[0]*s0; sxyz[r][1] = cp[1]*s1; sxyz[r][2] = cp[2]*s2;
        mtile[r] = (read_mask(maskp, mtype, (size_t)b*N_ + n) != 0) ? 1.f : 0.f;
      }
    }
    __syncthreads();
    {
      float px = sxyz[r][0], py = sxyz[r][1], pz = sxyz[r][2];
      #pragma unroll
      for (int i = 0; i < 4; ++i) {
        int idx = l + 16*i;
        if (idx < 32) {
          float u = px*omR[idx] + py*omR[32+idx];
          float sn, cs; sincosf(u, &sn, &cs);
          kc[r][64+idx] = cs*a0; kc[r][96+idx] = sn*a0;
        } else {
          int j = idx - 32;
          float u = pz*omA[j];
          float sn, cs; sincosf(u, &sn, &cs);
          kc[r][128+j] = cs*a1; kc[r][160+j] = sn*a1;
        }
      }
    }
    __syncthreads();
    {
      float s = 0.f;
      #pragma unroll
      for (int i = 0; i < 12; ++i) { float v = kc[r][l*12+i]; s += v*v; }
      red[r][l] = s;
    }
    __syncthreads();
    if (l == 0) {
      float s = 0.f;
      #pragma unroll
      for (int i = 0; i < 16; ++i) s += red[r][i];
      diag[r] = 0.5f*s;
    }
    __syncthreads();
    float dash[16];
    #pragma unroll
    for (int rr = 0; rr < 16; ++rr) dash[rr] = 0.f;
    const float4* pT = (const float4*)&W[OFF_PROJT];
    for (int dq = 0; dq < 48; ++dq) {
      float4 p = pT[dq*256 + tid];
      #pragma unroll
      for (int rr = 0; rr < 16; ++rr) {
        float4 c = *(const float4*)&kc[rr][dq*4];
        dash[rr] = fmaf(p.x, c.x, fmaf(p.y, c.y, fmaf(p.z, c.z, fmaf(p.w, c.w, dash[rr]))));
      }
    }
    #pragma unroll 1
    for (int rr = 0; rr < 16; ++rr) {
      float dv = dash[rr];
      maxd = fmaxf(maxd, dv);
      if (mtile[rr] != 0.f) {
        float E = expf(dv - diag[rr]);
        ksum_acc += E;
        const float4* v4p = (const float4*)&vt[rr][0];
        #pragma unroll
        for (int e4 = 0; e4 < 16; ++e4) {
          float4 v4 = v4p[e4];
          ctx[e4*4+0] = fmaf(E, v4.x, ctx[e4*4+0]);
          ctx[e4*4+1] = fmaf(E, v4.y, ctx[e4*4+1]);
          ctx[e4*4+2] = fmaf(E, v4.z, ctx[e4*4+2]);
          ctx[e4*4+3] = fmaf(E, v4.w, ctx[e4*4+3]);
        }
      }
    }
    if (tid < 64) {
      #pragma unroll 1
      for (int rr = 0; rr < 16; ++rr)
        if (mtile[rr] != 0.f) vs += vt[rr][tid];
    }
    if (tid == 0) {
      for (int rr = 0; rr < 16; ++rr) nm += mtile[rr];
    }
  }
  atomicAdd(&W[OFF_KSUM + bh*256 + tid], ksum_acc);
  float* ctxg = &W[OFF_CTX + ((size_t)bh*256 + tid)*64];
  for (int e = 0; e < 64; ++e) atomicAdd(&ctxg[e], ctx[e]);
  if (tid < 64) atomicAdd(&W[OFF_VSUM + bh*64 + tid], vs);
  if (tid == 0) atomicAdd(&W[OFF_NMASK + bh], nm);
  mred[tid] = maxd;
  __syncthreads();
  for (int s = 128; s > 0; s >>= 1) {
    if (tid < s) mred[tid] = fmaxf(mred[tid], mred[tid+s]);
    __syncthreads();
  }
  if (tid == 0) W[OFF_BMAX + blockIdx.x] = mred[0];
}

__global__ void k_mkred(float* __restrict__ W) {
  int i = threadIdx.x;
  if (i < 32) {
    float m = -INFINITY;
    for (int c = 0; c < NCH; ++c) m = fmaxf(m, W[OFF_BMAX + i*NCH + c]);
    W[OFF_MK + i] = m;
  }
}

__global__ __launch_bounds__(256)
void k_finalize(float* __restrict__ W) {
  int bh = blockIdx.x;
  int tid = threadIdx.x;
  float emk  = RATIO * expf(-W[OFF_MK + bh]);
  float epsr = RATIO * SM_EPS;
  float nm = W[OFF_NMASK + bh];
  {
    float* ks = &W[OFF_KSUM + bh*256];
    ks[tid] = emk*ks[tid] + epsr*nm;
  }
  float* ctx = &W[OFF_CTX + (size_t)bh*16384];
  const float* vsum = &W[OFF_VSUM + bh*64];
  for (int i = tid; i < 16384; i += 256) {
    int e = i & 63;
    ctx[i] = emk*ctx[i] + epsr*vsum[e];
  }
}

__global__ __launch_bounds__(256, 4)
void k_pass2(const float* __restrict__ query, const float* __restrict__ coords,
             const float* __restrict__ omR_g, const float* __restrict__ omA_g,
             const float* __restrict__ outb, const float* __restrict__ W,
             float* __restrict__ out) {
  int b  = blockIdx.x >> 9;          // N/16 = 512 tiles per batch
  int n0 = (blockIdx.x & 511) * 16;
  int tid = threadIdx.x;
  __shared__ __align__(16) float kc[16][192];
  __shared__ __align__(16) float qp[16][256];
  __shared__ __align__(16) float attn[16][64];
  __shared__ float ksl[256];
  __shared__ float sxyz[16][3];
  __shared__ float diag[16];
  __shared__ float mq[16];
  __shared__ float dnm[16];
  __shared__ float red[16][16];
  __shared__ float omR[64], omA[32];

  if (tid < 64) omR[tid] = omR_g[tid];
  if (tid < 32) omA[tid] = omA_g[tid];

  int r = tid >> 4, l = tid & 15;
  int rg = tid >> 6, e = tid & 63;
  float facc[4] = {0.f, 0.f, 0.f, 0.f};

  for (int h = 0; h < 8; ++h) {
    int bh = b*8 + h;
    float s0 = W[OFF_CONST + h*8 + 0];
    float s1 = W[OFF_CONST + h*8 + 1];
    float s2 = W[OFF_CONST + h*8 + 2];
    float a0 = W[OFF_CONST + h*8 + 3] * RFF_S;
    float a1 = W[OFF_CONST + h*8 + 4] * RFF_S;
    __syncthreads();
    ksl[tid] = W[OFF_KSUM + bh*256 + tid];
    {
      int n = n0 + r;
      const float* qpr = query + ((size_t)b*N_ + n)*512 + h*64 + l*4;
      float4 qv = *(const float4*)qpr;
      kc[r][l*4+0] = qv.x*SQT; kc[r][l*4+1] = qv.y*SQT;
      kc[r][l*4+2] = qv.z*SQT; kc[r][l*4+3] = qv.w*SQT;
      if (l == 0) {
        const float* cp = coords + ((size_t)b*N_ + n)*3;
        sxyz[r][0] = cp[0]*s0; sxyz[r][1] = cp[1]*s1; sxyz[r][2] = cp[2]*s2;
      }
    }
    __syncthreads();
    {
      float px = sxyz[r][0], py = sxyz[r][1], pz = sxyz[r][2];
      #pragma unroll
      for (int i = 0; i < 4; ++i) {
        int idx = l + 16*i;
        if (idx < 32) {
          float u = px*omR[idx] + py*omR[32+idx];
          float sn, cs; sincosf(u, &sn, &cs);
          kc[r][64+idx] = cs*a0; kc[r][96+idx] = sn*a0;
        } else {
          int j = idx - 32;
          float u = pz*omA[j];
          float sn, cs; sincosf(u, &sn, &cs);
          kc[r][128+j] = cs*a1; kc[r][160+j] = sn*a1;
        }
      }
    }
    __syncthreads();
    {
      float s = 0.f;
      #pragma unroll
      for (int i = 0; i < 12; ++i) { float v = kc[r][l*12+i]; s += v*v; }
      red[r][l] = s;
    }
    __syncthreads();
    if (l == 0) {
      float s = 0.f;
      #pragma unroll
      for (int i = 0; i < 16; ++i) s += red[r][i];
      diag[r] = 0.5f*s;
    }
    __syncthreads();
    float dash[16];
    #pragma unroll
    for (int rr = 0; rr < 16; ++rr) dash[rr] = 0.f;
    const float4* pT = (const float4*)&W[OFF_PROJT];
    for (int dq = 0; dq < 48; ++dq) {
      float4 p = pT[dq*256 + tid];
      #pragma unroll
      for (int rr = 0; rr < 16; ++rr) {
        float4 c = *(const float4*)&kc[rr][dq*4];
        dash[rr] = fmaf(p.x, c.x, fmaf(p.y, c.y, fmaf(p.z, c.z, fmaf(p.w, c.w, dash[rr]))));
      }
    }
    #pragma unroll
    for (int rr = 0; rr < 16; ++rr) qp[rr][tid] = dash[rr];
    __syncthreads();
    {
      float m = -INFINITY;
      for (int fi = l; fi < 256; fi += 16) m = fmaxf(m, qp[r][fi]);
      red[r][l] = m;
    }
    __syncthreads();
    if (l == 0) {
      float m = -INFINITY;
      #pragma unroll
      for (int i = 0; i < 16; ++i) m = fmaxf(m, red[r][i]);
      mq[r] = m;
    }
    __syncthreads();
    #pragma unroll
    for (int rr = 0; rr < 16; ++rr) {
      float qv = RATIO * (expf(qp[rr][tid] - diag[rr] - mq[rr]) + SM_EPS);
      qp[rr][tid] = qv;
    }
    __syncthreads();
    {
      float s = 0.f;
      for (int fi = l; fi < 256; fi += 16) s += qp[r][fi] * ksl[fi];
      red[r][l] = s;
    }
    __syncthreads();
    if (l == 0) {
      float s = 0.f;
      #pragma unroll
      for (int i = 0; i < 16; ++i) s += red[r][i];
      dnm[r] = 1.f / (s + NORM_EPS);
    }
    __syncthreads();
    {
      const float* ctxg = &W[OFF_CTX + (size_t)bh*16384];
      float acc[4] = {0.f, 0.f, 0.f, 0.f};
      for (int fi = 0; fi < 256; ++fi) {
        float cx = ctxg[fi*64 + e];
        #pragma unroll
        for (int i = 0; i < 4; ++i) acc[i] = fmaf(qp[rg*4+i][fi], cx, acc[i]);
      }
      #pragma unroll
      for (int i = 0; i < 4; ++i) attn[rg*4+i][e] = acc[i] * dnm[rg*4+i];
    }
    __syncthreads();
    {
      const float* owT = &W[OFF_OWT + h*64*64];
      #pragma unroll 1
      for (int ee = 0; ee < 64; ++ee) {
        float wv = owT[ee*64 + e];
        #pragma unroll
        for (int i = 0; i < 4; ++i) facc[i] = fmaf(attn[rg*4+i][ee], wv, facc[i]);
      }
    }
  }
  {
    float bj = outb[e];
    #pragma unroll
    for (int i = 0; i < 4; ++i) {
      int n = n0 + rg*4 + i;
      out[((size_t)b*N_ + n)*64 + e] = facc[i] + bj;
    }
  }
}

extern "C" void kernel_launch(void* const* d_in, const int* in_sizes, int n_in,
                              void* d_out, int out_size, void* d_ws, size_t ws_size,
                              hipStream_t stream) {
  const float* query  = (const float*)d_in[0];
  const float* key    = (const float*)d_in[1];
  const float* value  = (const float*)d_in[2];
  const float* coords = (const float*)d_in[3];
  const void*  mask   = d_in[4];
  const float* wrpe   = (const float*)d_in[5];
  const float* omR    = (const float*)d_in[6];
  const float* omA    = (const float*)d_in[7];
  const float* proj   = (const float*)d_in[8];
  const float* outw   = (const float*)d_in[9];
  const float* outb   = (const float*)d_in[10];
  float* W = (float*)d_ws;
  float* out = (float*)d_out;

  hipMemsetAsync(W + ZERO_BEG, 0, (size_t)(ZERO_END - ZERO_BEG)*sizeof(float), stream);
  hipLaunchKernelGGL(k_consts,   dim3(1),        dim3(256), 0, stream, wrpe, proj, outw,
                     (const unsigned int*)mask, W);
  hipLaunchKernelGGL(k_pass1,    dim3(32*NCH),   dim3(256), 0, stream, key, value, coords, mask, omR, omA, W);
  hipLaunchKernelGGL(k_mkred,    dim3(1),        dim3(64),  0, stream, W);
  hipLaunchKernelGGL(k_finalize, dim3(32),       dim3(256), 0, stream, W);
  hipLaunchKernelGGL(k_pass2,    dim3(2048),     dim3(256), 0, stream, query, coords, omR, omA, outb, W, out);
}

// Round 7
// 2293.693 us; speedup vs baseline: 1.3531x; 1.3531x over previous
//
#include <hip/hip_runtime.h>
#include <hip/hip_bf16.h>
#include <math.h>

constexpr int B_ = 4, N_ = 8192, H_ = 8;
constexpr float SQT    = 0.35355339059327373f;   // sqrt(SOFTMAX_TEMP)
constexpr float RFF_S  = 0.17677669529663687f;   // sqrt(2/64)
constexpr float RATIO  = 0.0625f;                // 256^-0.5
constexpr float SM_EPS = 1e-6f;
constexpr float NORM_EPS = 1e-6f;

// pass1 chunking: 2 blocks/CU (VGPR-limited residency), zero spill is the goal
constexpr int NCH = 16, CHUNK = N_ / NCH;        // 512 rows/block, grid 512

// ws layout (float offsets)
constexpr int OFF_CONST = 0;        // 64
constexpr int OFF_FLAG  = 63;       // mask dtype flag
constexpr int OFF_MK    = 64;       // 32
constexpr int OFF_NMASK = 96;       // 32
constexpr int OFF_KSUM  = 128;      // 32*256
constexpr int OFF_VSUM  = 8320;     // 32*64
constexpr int OFF_BMAX  = 10368;    // 32*NCH = 512
constexpr int OFF_CTX   = 10880;    // 32*256*64
constexpr int OFF_PROJT = 535168;   // 48*256*4
constexpr int OFF_OWT   = 584320;   // 512*64
constexpr int ZERO_BEG  = OFF_NMASK;
constexpr int ZERO_END  = OFF_CTX + 32*16384;

__global__ __launch_bounds__(256)
void k_consts(const float* __restrict__ wrpe, const float* __restrict__ proj,
              const float* __restrict__ outw, const unsigned int* __restrict__ maskw,
              float* __restrict__ W) {
  __shared__ float exs[128];
  __shared__ float qwv[8][2];
  __shared__ int f_gt1, f_oddnz, f_evennz;
  int tid = threadIdx.x;
  if (tid == 0) { f_gt1 = 0; f_oddnz = 0; f_evennz = 0; }
  __syncthreads();
  {
    int gt1 = 0, oddnz = 0, evennz = 0;
    for (int i = tid; i < 8192; i += 256) {
      unsigned int v = maskw[i];
      if (v > 1u) gt1 = 1;
      if (v != 0u) { if (i & 1) oddnz = 1; else evennz = 1; }
    }
    if (gt1)    atomicOr(&f_gt1, 1);
    if (oddnz)  atomicOr(&f_oddnz, 1);
    if (evennz) atomicOr(&f_evennz, 1);
  }
  if (tid < 128) {
    int h = tid >> 4, r = (tid >> 3) & 1, c = (tid >> 2) & 1, k = tid & 3;
    float s = 0.f;
    for (int d = 0; d < 64; ++d) s += wrpe[(h*64 + d)*16 + r*8 + c*4 + k];
    exs[tid] = expf(fminf(s, 50.f));
  }
  __syncthreads();
  if (tid == 0) {
    float flag = 0.f;
    if (f_gt1) flag = 1.f;
    else if (!f_oddnz && f_evennz) flag = 2.f;
    W[OFF_FLAG] = flag;
  }
  if (tid < 32) {
    int h = tid >> 2, r = (tid >> 1) & 1, c = tid & 1;
    float s = 0.f;
    for (int k = 0; k < 4; ++k) s += exs[h*16 + r*8 + c*4 + k];
    if (c == 0) W[OFF_CONST + h*8 + 3 + r] = sqrtf(s);   // sqrt(alpha[h][r])
    else        qwv[h][r] = s;
  }
  __syncthreads();
  if (tid < 8) {
    int h = tid;
    float s0 = sqrtf(qwv[h][0]), s1 = sqrtf(qwv[h][1]);
    W[OFF_CONST + h*8 + 0] = s0;   // new_qw = [qw0, qw0, qw1]
    W[OFF_CONST + h*8 + 1] = s0;
    W[OFF_CONST + h*8 + 2] = s1;
  }
  for (int i = tid; i < 32*NCH; i += 256) W[OFF_BMAX + i] = -INFINITY;
  // projT4[(dq*256+f)*4 + j] = proj[f*192 + dq*4 + j]
  for (int i = tid; i < 48*256; i += 256) {
    int dq = i >> 8, f = i & 255;
    float4 v = *(const float4*)&proj[f*192 + dq*4];
    *(float4*)&W[OFF_PROJT + i*4] = v;
  }
  // out_wT[c][j] = out_w[j][c]
  for (int i = tid; i < 512*64; i += 256) {
    int c = i >> 6, j = i & 63;
    W[OFF_OWT + c*64 + j] = outw[j*512 + c];
  }
}

__device__ __forceinline__ int read_mask(const void* maskp, int mtype, size_t idx) {
  if (mtype == 1) return (int)((const unsigned char*)maskp)[idx];
  if (mtype == 2) return (int)((const long long*)maskp)[idx];
  return ((const int*)maskp)[idx];
}

__global__ __launch_bounds__(256, 2)   // VGPR cap 256: ctx[64]+dash[16] stay in registers
void k_pass1(const float* __restrict__ key, const float* __restrict__ value,
             const float* __restrict__ coords, const void* __restrict__ maskp,
             const float* __restrict__ omR_g, const float* __restrict__ omA_g,
             float* __restrict__ W) {
  int bh = blockIdx.x / NCH, ch = blockIdx.x % NCH;
  int b = bh >> 3, h = bh & 7;
  int tid = threadIdx.x;
  __shared__ __align__(16) float kc[16][192];
  __shared__ __align__(16) float vt[16][64];
  __shared__ float sxyz[16][3];
  __shared__ float mtile[16];
  __shared__ float diag[16];
  __shared__ float red[16][16];
  __shared__ float omR[64], omA[32];
  __shared__ float mred[256];

  if (tid < 64) omR[tid] = omR_g[tid];
  if (tid < 32) omA[tid] = omA_g[tid];
  int mtype = (int)W[OFF_FLAG];
  float s0 = W[OFF_CONST + h*8 + 0];
  float s1 = W[OFF_CONST + h*8 + 1];
  float s2 = W[OFF_CONST + h*8 + 2];
  float a0 = W[OFF_CONST + h*8 + 3] * RFF_S;
  float a1 = W[OFF_CONST + h*8 + 4] * RFF_S;

  float ctx[64];
  #pragma unroll
  for (int e = 0; e < 64; ++e) ctx[e] = 0.f;
  float ksum_acc = 0.f, maxd = -INFINITY;
  float vs = 0.f, nm = 0.f;

  int r = tid >> 4, l = tid & 15;
  for (int t = 0; t < CHUNK/16; ++t) {
    int n = ch*CHUNK + t*16 + r;
    __syncthreads();
    {
      const float* kp = key + ((size_t)b*N_ + n)*512 + h*64 + l*4;
      float4 kv = *(const float4*)kp;
      kc[r][l*4+0] = kv.x*SQT; kc[r][l*4+1] = kv.y*SQT;
      kc[r][l*4+2] = kv.z*SQT; kc[r][l*4+3] = kv.w*SQT;
      const float* vp = value + ((size_t)b*N_ + n)*512 + h*64 + l*4;
      *(float4*)&vt[r][l*4] = *(const float4*)vp;
      if (l == 0) {
        const float* cp = coords + ((size_t)b*N_ + n)*3;
        sxyz[r][0] = cp[0]*s0; sxyz[r][1] = cp[1]*s1; sxyz[r][2] = cp[2]*s2;
        mtile[r] = (read_mask(maskp, mtype, (size_t)b*N_ + n) != 0) ? 1.f : 0.f;
      }
    }
    __syncthreads();
    {
      float px = sxyz[r][0], py = sxyz[r][1], pz = sxyz[r][2];
      #pragma unroll
      for (int i = 0; i < 4; ++i) {
        int idx = l + 16*i;
        if (idx < 32) {
          float u = px*omR[idx] + py*omR[32+idx];
          float sn, cs; sincosf(u, &sn, &cs);
          kc[r][64+idx] = cs*a0; kc[r][96+idx] = sn*a0;
        } else {
          int j = idx - 32;
          float u = pz*omA[j];
          float sn, cs; sincosf(u, &sn, &cs);
          kc[r][128+j] = cs*a1; kc[r][160+j] = sn*a1;
        }
      }
    }
    __syncthreads();
    {
      float s = 0.f;
      #pragma unroll
      for (int i = 0; i < 12; ++i) { float v = kc[r][l*12+i]; s += v*v; }
      red[r][l] = s;
    }
    __syncthreads();
    if (l == 0) {
      float s = 0.f;
      #pragma unroll
      for (int i = 0; i < 16; ++i) s += red[r][i];
      diag[r] = 0.5f*s;
    }
    __syncthreads();
    float dash[16];
    #pragma unroll
    for (int rr = 0; rr < 16; ++rr) dash[rr] = 0.f;
    const float4* pT = (const float4*)&W[OFF_PROJT];
    for (int dq = 0; dq < 48; ++dq) {
      float4 p = pT[dq*256 + tid];
      #pragma unroll
      for (int rr = 0; rr < 16; ++rr) {
        float4 c = *(const float4*)&kc[rr][dq*4];
        dash[rr] = fmaf(p.x, c.x, fmaf(p.y, c.y, fmaf(p.z, c.z, fmaf(p.w, c.w, dash[rr]))));
      }
    }
    #pragma unroll 1
    for (int rr = 0; rr < 16; ++rr) {
      float dv = dash[rr];
      maxd = fmaxf(maxd, dv);
      if (mtile[rr] != 0.f) {
        float E = expf(dv - diag[rr]);
        ksum_acc += E;
        const float4* v4p = (const float4*)&vt[rr][0];
        #pragma unroll
        for (int e4 = 0; e4 < 16; ++e4) {
          float4 v4 = v4p[e4];
          ctx[e4*4+0] = fmaf(E, v4.x, ctx[e4*4+0]);
          ctx[e4*4+1] = fmaf(E, v4.y, ctx[e4*4+1]);
          ctx[e4*4+2] = fmaf(E, v4.z, ctx[e4*4+2]);
          ctx[e4*4+3] = fmaf(E, v4.w, ctx[e4*4+3]);
        }
      }
    }
    if (tid < 64) {
      #pragma unroll 1
      for (int rr = 0; rr < 16; ++rr)
        if (mtile[rr] != 0.f) vs += vt[rr][tid];
    }
    if (tid == 0) {
      for (int rr = 0; rr < 16; ++rr) nm += mtile[rr];
    }
  }
  atomicAdd(&W[OFF_KSUM + bh*256 + tid], ksum_acc);
  float* ctxg = &W[OFF_CTX + ((size_t)bh*256 + tid)*64];
  for (int e = 0; e < 64; ++e) atomicAdd(&ctxg[e], ctx[e]);
  if (tid < 64) atomicAdd(&W[OFF_VSUM + bh*64 + tid], vs);
  if (tid == 0) atomicAdd(&W[OFF_NMASK + bh], nm);
  mred[tid] = maxd;
  __syncthreads();
  for (int s = 128; s > 0; s >>= 1) {
    if (tid < s) mred[tid] = fmaxf(mred[tid], mred[tid+s]);
    __syncthreads();
  }
  if (tid == 0) W[OFF_BMAX + blockIdx.x] = mred[0];
}

__global__ void k_mkred(float* __restrict__ W) {
  int i = threadIdx.x;
  if (i < 32) {
    float m = -INFINITY;
    for (int c = 0; c < NCH; ++c) m = fmaxf(m, W[OFF_BMAX + i*NCH + c]);
    W[OFF_MK + i] = m;
  }
}

__global__ __launch_bounds__(256)
void k_finalize(float* __restrict__ W) {
  int bh = blockIdx.x;
  int tid = threadIdx.x;
  float emk  = RATIO * expf(-W[OFF_MK + bh]);
  float epsr = RATIO * SM_EPS;
  float nm = W[OFF_NMASK + bh];
  {
    float* ks = &W[OFF_KSUM + bh*256];
    ks[tid] = emk*ks[tid] + epsr*nm;
  }
  float* ctx = &W[OFF_CTX + (size_t)bh*16384];
  const float* vsum = &W[OFF_VSUM + bh*64];
  for (int i = tid; i < 16384; i += 256) {
    int e = i & 63;
    ctx[i] = emk*ctx[i] + epsr*vsum[e];
  }
}

__global__ __launch_bounds__(256)
void k_pass2(const float* __restrict__ query, const float* __restrict__ coords,
             const float* __restrict__ omR_g, const float* __restrict__ omA_g,
             const float* __restrict__ outb, const float* __restrict__ W,
             float* __restrict__ out) {
  int b  = blockIdx.x >> 9;          // N/16 = 512 tiles per batch
  int n0 = (blockIdx.x & 511) * 16;
  int tid = threadIdx.x;
  __shared__ __align__(16) float kc[16][192];
  __shared__ __align__(16) float qp[16][256];
  __shared__ __align__(16) float attn[16][64];
  __shared__ float ksl[256];
  __shared__ float sxyz[16][3];
  __shared__ float diag[16];
  __shared__ float mq[16];
  __shared__ float dnm[16];
  __shared__ float red[16][16];
  __shared__ float omR[64], omA[32];

  if (tid < 64) omR[tid] = omR_g[tid];
  if (tid < 32) omA[tid] = omA_g[tid];

  int r = tid >> 4, l = tid & 15;
  int rg = tid >> 6, e = tid & 63;
  float facc[4] = {0.f, 0.f, 0.f, 0.f};

  for (int h = 0; h < 8; ++h) {
    int bh = b*8 + h;
    float s0 = W[OFF_CONST + h*8 + 0];
    float s1 = W[OFF_CONST + h*8 + 1];
    float s2 = W[OFF_CONST + h*8 + 2];
    float a0 = W[OFF_CONST + h*8 + 3] * RFF_S;
    float a1 = W[OFF_CONST + h*8 + 4] * RFF_S;
    __syncthreads();
    ksl[tid] = W[OFF_KSUM + bh*256 + tid];
    {
      int n = n0 + r;
      const float* qpr = query + ((size_t)b*N_ + n)*512 + h*64 + l*4;
      float4 qv = *(const float4*)qpr;
      kc[r][l*4+0] = qv.x*SQT; kc[r][l*4+1] = qv.y*SQT;
      kc[r][l*4+2] = qv.z*SQT; kc[r][l*4+3] = qv.w*SQT;
      if (l == 0) {
        const float* cp = coords + ((size_t)b*N_ + n)*3;
        sxyz[r][0] = cp[0]*s0; sxyz[r][1] = cp[1]*s1; sxyz[r][2] = cp[2]*s2;
      }
    }
    __syncthreads();
    {
      float px = sxyz[r][0], py = sxyz[r][1], pz = sxyz[r][2];
      #pragma unroll
      for (int i = 0; i < 4; ++i) {
        int idx = l + 16*i;
        if (idx < 32) {
          float u = px*omR[idx] + py*omR[32+idx];
          float sn, cs; sincosf(u, &sn, &cs);
          kc[r][64+idx] = cs*a0; kc[r][96+idx] = sn*a0;
        } else {
          int j = idx - 32;
          float u = pz*omA[j];
          float sn, cs; sincosf(u, &sn, &cs);
          kc[r][128+j] = cs*a1; kc[r][160+j] = sn*a1;
        }
      }
    }
    __syncthreads();
    {
      float s = 0.f;
      #pragma unroll
      for (int i = 0; i < 12; ++i) { float v = kc[r][l*12+i]; s += v*v; }
      red[r][l] = s;
    }
    __syncthreads();
    if (l == 0) {
      float s = 0.f;
      #pragma unroll
      for (int i = 0; i < 16; ++i) s += red[r][i];
      diag[r] = 0.5f*s;
    }
    __syncthreads();
    float dash[16];
    #pragma unroll
    for (int rr = 0; rr < 16; ++rr) dash[rr] = 0.f;
    const float4* pT = (const float4*)&W[OFF_PROJT];
    for (int dq = 0; dq < 48; ++dq) {
      float4 p = pT[dq*256 + tid];
      #pragma unroll
      for (int rr = 0; rr < 16; ++rr) {
        float4 c = *(const float4*)&kc[rr][dq*4];
        dash[rr] = fmaf(p.x, c.x, fmaf(p.y, c.y, fmaf(p.z, c.z, fmaf(p.w, c.w, dash[rr]))));
      }
    }
    #pragma unroll
    for (int rr = 0; rr < 16; ++rr) qp[rr][tid] = dash[rr];
    __syncthreads();
    {
      float m = -INFINITY;
      for (int fi = l; fi < 256; fi += 16) m = fmaxf(m, qp[r][fi]);
      red[r][l] = m;
    }
    __syncthreads();
    if (l == 0) {
      float m = -INFINITY;
      #pragma unroll
      for (int i = 0; i < 16; ++i) m = fmaxf(m, red[r][i]);
      mq[r] = m;
    }
    __syncthreads();
    #pragma unroll
    for (int rr = 0; rr < 16; ++rr) {
      float qv = RATIO * (expf(qp[rr][tid] - diag[rr] - mq[rr]) + SM_EPS);
      qp[rr][tid] = qv;
    }
    __syncthreads();
    {
      float s = 0.f;
      for (int fi = l; fi < 256; fi += 16) s += qp[r][fi] * ksl[fi];
      red[r][l] = s;
    }
    __syncthreads();
    if (l == 0) {
      float s = 0.f;
      #pragma unroll
      for (int i = 0; i < 16; ++i) s += red[r][i];
      dnm[r] = 1.f / (s + NORM_EPS);
    }
    __syncthreads();
    {
      const float* ctxg = &W[OFF_CTX + (size_t)bh*16384];
      float acc[4] = {0.f, 0.f, 0.f, 0.f};
      for (int fi = 0; fi < 256; ++fi) {
        float cx = ctxg[fi*64 + e];
        #pragma unroll
        for (int i = 0; i < 4; ++i) acc[i] = fmaf(qp[rg*4+i][fi], cx, acc[i]);
      }
      #pragma unroll
      for (int i = 0; i < 4; ++i) attn[rg*4+i][e] = acc[i] * dnm[rg*4+i];
    }
    __syncthreads();
    {
      const float* owT = &W[OFF_OWT + h*64*64];
      #pragma unroll 1
      for (int ee = 0; ee < 64; ++ee) {
        float wv = owT[ee*64 + e];
        #pragma unroll
        for (int i = 0; i < 4; ++i) facc[i] = fmaf(attn[rg*4+i][ee], wv, facc[i]);
      }
    }
  }
  {
    float bj = outb[e];
    #pragma unroll
    for (int i = 0; i < 4; ++i) {
      int n = n0 + rg*4 + i;
      out[((size_t)b*N_ + n)*64 + e] = facc[i] + bj;
    }
  }
}

extern "C" void kernel_launch(void* const* d_in, const int* in_sizes, int n_in,
                              void* d_out, int out_size, void* d_ws, size_t ws_size,
                              hipStream_t stream) {
  const float* query  = (const float*)d_in[0];
  const float* key    = (const float*)d_in[1];
  const float* value  = (const float*)d_in[2];
  const float* coords = (const float*)d_in[3];
  const void*  mask   = d_in[4];
  const float* wrpe   = (const float*)d_in[5];
  const float* omR    = (const float*)d_in[6];
  const float* omA    = (const float*)d_in[7];
  const float* proj   = (const float*)d_in[8];
  const float* outw   = (const float*)d_in[9];
  const float* outb   = (const float*)d_in[10];
  float* W = (float*)d_ws;
  float* out = (float*)d_out;

  hipMemsetAsync(W + ZERO_BEG, 0, (size_t)(ZERO_END - ZERO_BEG)*sizeof(float), stream);
  hipLaunchKernelGGL(k_consts,   dim3(1),        dim3(256), 0, stream, wrpe, proj, outw,
                     (const unsigned int*)mask, W);
  hipLaunchKernelGGL(k_pass1,    dim3(32*NCH),   dim3(256), 0, stream, key, value, coords, mask, omR, omA, W);
  hipLaunchKernelGGL(k_mkred,    dim3(1),        dim3(64),  0, stream, W);
  hipLaunchKernelGGL(k_finalize, dim3(32),       dim3(256), 0, stream, W);
  hipLaunchKernelGGL(k_pass2,    dim3(2048),     dim3(256), 0, stream, query, coords, omR, omA, outb, W, out);
}

// Round 8
// 1178.564 us; speedup vs baseline: 2.6333x; 1.9462x over previous
//
#include <hip/hip_runtime.h>
#include <hip/hip_bf16.h>
#include <math.h>

constexpr int B_ = 4, N_ = 8192, H_ = 8;
constexpr float SQT    = 0.35355339059327373f;   // sqrt(SOFTMAX_TEMP)
constexpr float RFF_S  = 0.17677669529663687f;   // sqrt(2/64)
constexpr float RATIO  = 0.0625f;                // 256^-0.5
constexpr float SM_EPS = 1e-6f;
constexpr float NORM_EPS = 1e-6f;

constexpr int NCH = 16, CHUNK = N_ / NCH;        // 512 rows/block, grid 512

// ws layout (float offsets)
constexpr int OFF_CONST = 0;
constexpr int OFF_FLAG  = 63;
constexpr int OFF_MK    = 64;
constexpr int OFF_NMASK = 96;
constexpr int OFF_KSUM  = 128;      // 32*256
constexpr int OFF_VSUM  = 8320;     // 32*64
constexpr int OFF_BMAX  = 10368;    // 512
constexpr int OFF_CTX   = 10880;    // 32*256*64
constexpr int OFF_PROJT = 535168;   // 48*256*4 (f32, pass2)
constexpr int OFF_OWT   = 584320;   // 512*64
constexpr int ZERO_BEG  = OFF_NMASK;
constexpr int ZERO_END  = OFF_CTX + 32*16384;

typedef __attribute__((ext_vector_type(8))) short short8v;
typedef __attribute__((ext_vector_type(4))) float f32x4;

__device__ __forceinline__ unsigned short f2bs(float x) {
  union { float f; unsigned int u; } v; v.f = x;
  unsigned int r = v.u + 0x7fffu + ((v.u >> 16) & 1u);
  return (unsigned short)(r >> 16);
}
__device__ __forceinline__ float bs2f(unsigned short s) {
  union { unsigned int u; float f; } v; v.u = ((unsigned int)s) << 16;
  return v.f;
}

__global__ __launch_bounds__(256)
void k_consts(const float* __restrict__ wrpe, const float* __restrict__ proj,
              const float* __restrict__ outw, const unsigned int* __restrict__ maskw,
              float* __restrict__ W) {
  __shared__ float exs[128];
  __shared__ float qwv[8][2];
  __shared__ int f_gt1, f_oddnz, f_evennz;
  int tid = threadIdx.x;
  if (tid == 0) { f_gt1 = 0; f_oddnz = 0; f_evennz = 0; }
  __syncthreads();
  {
    int gt1 = 0, oddnz = 0, evennz = 0;
    for (int i = tid; i < 8192; i += 256) {
      unsigned int v = maskw[i];
      if (v > 1u) gt1 = 1;
      if (v != 0u) { if (i & 1) oddnz = 1; else evennz = 1; }
    }
    if (gt1)    atomicOr(&f_gt1, 1);
    if (oddnz)  atomicOr(&f_oddnz, 1);
    if (evennz) atomicOr(&f_evennz, 1);
  }
  if (tid < 128) {
    int h = tid >> 4, r = (tid >> 3) & 1, c = (tid >> 2) & 1, k = tid & 3;
    float s = 0.f;
    for (int d = 0; d < 64; ++d) s += wrpe[(h*64 + d)*16 + r*8 + c*4 + k];
    exs[tid] = expf(fminf(s, 50.f));
  }
  __syncthreads();
  if (tid == 0) {
    float flag = 0.f;
    if (f_gt1) flag = 1.f;
    else if (!f_oddnz && f_evennz) flag = 2.f;
    W[OFF_FLAG] = flag;
  }
  if (tid < 32) {
    int h = tid >> 2, r = (tid >> 1) & 1, c = tid & 1;
    float s = 0.f;
    for (int k = 0; k < 4; ++k) s += exs[h*16 + r*8 + c*4 + k];
    if (c == 0) W[OFF_CONST + h*8 + 3 + r] = sqrtf(s);
    else        qwv[h][r] = s;
  }
  __syncthreads();
  if (tid < 8) {
    int h = tid;
    float s0 = sqrtf(qwv[h][0]), s1 = sqrtf(qwv[h][1]);
    W[OFF_CONST + h*8 + 0] = s0;
    W[OFF_CONST + h*8 + 1] = s0;
    W[OFF_CONST + h*8 + 2] = s1;
  }
  for (int i = tid; i < 512; i += 256) W[OFF_BMAX + i] = -INFINITY;
  for (int i = tid; i < 48*256; i += 256) {
    int dq = i >> 8, f = i & 255;
    float4 v = *(const float4*)&proj[f*192 + dq*4];
    *(float4*)&W[OFF_PROJT + i*4] = v;
  }
  for (int i = tid; i < 512*64; i += 256) {
    int c = i >> 6, j = i & 63;
    W[OFF_OWT + c*64 + j] = outw[j*512 + c];
  }
}

__device__ __forceinline__ int read_mask(const void* maskp, int mtype, size_t idx) {
  if (mtype == 1) return (int)((const unsigned char*)maskp)[idx];
  if (mtype == 2) return (int)((const long long*)maskp)[idx];
  return ((const int*)maskp)[idx];
}

__global__ __launch_bounds__(256, 2)
void k_pass1(const float* __restrict__ key, const float* __restrict__ value,
             const float* __restrict__ coords, const void* __restrict__ maskp,
             const float* __restrict__ omR_g, const float* __restrict__ omA_g,
             const float* __restrict__ proj, float* __restrict__ W) {
  int bh = blockIdx.x / NCH, ch = blockIdx.x % NCH;
  int b = bh >> 3, h = bh & 7;
  int tid = threadIdx.x;
  int w = tid >> 6, lane = tid & 63, g = lane >> 4, fcol = lane & 15, g4 = g*4;

  __shared__ __align__(16) unsigned short kcb[32][200];  // bf16 features, 400B rows
  __shared__ __align__(16) unsigned short vtT[64][40];   // v transposed [e][n]
  __shared__ __align__(16) unsigned short eT[256][40];   // E^T [f][n]
  __shared__ float red[32][8];
  __shared__ float diag_s[32];
  __shared__ float mtile_s[32];
  __shared__ float mred[256];
  __shared__ float omR[64], omA[32];

  if (tid < 64) omR[tid] = omR_g[tid];
  if (tid < 32) omA[tid] = omA_g[tid];
  int mtype = (int)W[OFF_FLAG];
  float s0 = W[OFF_CONST + h*8 + 0];
  float s1 = W[OFF_CONST + h*8 + 1];
  float s2 = W[OFF_CONST + h*8 + 2];
  float a0 = W[OFF_CONST + h*8 + 3] * RFF_S;
  float a1 = W[OFF_CONST + h*8 + 4] * RFF_S;

  // Preload proj B-fragments (bf16) into registers: pb[ftile][kstep]
  short8v pb[4][6];
  #pragma unroll
  for (int ft = 0; ft < 4; ++ft) {
    int f = w*64 + ft*16 + fcol;
    #pragma unroll
    for (int ks = 0; ks < 6; ++ks) {
      const float* p = proj + (size_t)f*192 + ks*32 + g*8;
      float4 p0 = *(const float4*)p;
      float4 p1 = *(const float4*)(p + 4);
      short8v v;
      v[0]=f2bs(p0.x); v[1]=f2bs(p0.y); v[2]=f2bs(p0.z); v[3]=f2bs(p0.w);
      v[4]=f2bs(p1.x); v[5]=f2bs(p1.y); v[6]=f2bs(p1.z); v[7]=f2bs(p1.w);
      pb[ft][ks] = v;
    }
  }

  f32x4 ctx[4][4];
  #pragma unroll
  for (int i = 0; i < 4; ++i)
    #pragma unroll
    for (int j = 0; j < 4; ++j) ctx[i][j] = (f32x4){0.f,0.f,0.f,0.f};
  float ksum_p[4] = {0.f,0.f,0.f,0.f};
  float maxd = -INFINITY, vs = 0.f, nm = 0.f;

  int srow = tid >> 3, sc = tid & 7;   // staging map: row 0..31, col-chunk 0..7

  for (int t = 0; t < CHUNK/32; ++t) {
    int n0 = ch*CHUNK + t*32;
    __syncthreads();   // protect LDS reuse
    // ---- stage: key->kcb, value->vtT, RFF->kcb, sq partials, mask ----
    {
      size_t nidx = (size_t)b*N_ + n0 + srow;
      const float* kp = key + nidx*512 + h*64 + sc*8;
      const float* vp = value + nidx*512 + h*64 + sc*8;
      float4 k0 = *(const float4*)kp, k1 = *(const float4*)(kp+4);
      float4 v0 = *(const float4*)vp, v1 = *(const float4*)(vp+4);
      float kk[8] = {k0.x*SQT,k0.y*SQT,k0.z*SQT,k0.w*SQT,k1.x*SQT,k1.y*SQT,k1.z*SQT,k1.w*SQT};
      float sq = 0.f;
      short8v kv;
      #pragma unroll
      for (int i = 0; i < 8; ++i) { sq += kk[i]*kk[i]; kv[i] = f2bs(kk[i]); }
      *(short8v*)&kcb[srow][sc*8] = kv;
      float vv[8] = {v0.x,v0.y,v0.z,v0.w,v1.x,v1.y,v1.z,v1.w};
      #pragma unroll
      for (int i = 0; i < 8; ++i) vtT[sc*8+i][srow] = f2bs(vv[i]);
      const float* cp = coords + nidx*3;
      float px = cp[0]*s0, py = cp[1]*s1, pz = cp[2]*s2;
      #pragma unroll
      for (int ii = 0; ii < 8; ++ii) {
        int idx = sc*8 + ii;
        float sn, cs;
        if (idx < 32) {
          float u = px*omR[idx] + py*omR[32+idx];
          __sincosf(u, &sn, &cs);
          float cv = cs*a0, sv = sn*a0;
          kcb[srow][64+idx] = f2bs(cv); kcb[srow][96+idx] = f2bs(sv);
          sq += cv*cv + sv*sv;
        } else {
          int j = idx - 32;
          float u = pz*omA[j];
          __sincosf(u, &sn, &cs);
          float cv = cs*a1, sv = sn*a1;
          kcb[srow][128+j] = f2bs(cv); kcb[srow][160+j] = f2bs(sv);
          sq += cv*cv + sv*sv;
        }
      }
      red[srow][sc] = sq;
      if (tid < 32)
        mtile_s[tid] = (read_mask(maskp, mtype, (size_t)b*N_ + n0 + tid) != 0) ? 1.f : 0.f;
    }
    __syncthreads();
    // ---- dash MFMAs + diag reduce ----
    f32x4 dlo[4], dhi[4];
    #pragma unroll
    for (int ft = 0; ft < 4; ++ft) { dlo[ft] = (f32x4){0,0,0,0}; dhi[ft] = (f32x4){0,0,0,0}; }
    #pragma unroll
    for (int ks = 0; ks < 6; ++ks) {
      short8v alo = *(const short8v*)&kcb[fcol][ks*32 + g*8];
      short8v ahi = *(const short8v*)&kcb[16+fcol][ks*32 + g*8];
      #pragma unroll
      for (int ft = 0; ft < 4; ++ft) {
        dlo[ft] = __builtin_amdgcn_mfma_f32_16x16x32_bf16(alo, pb[ft][ks], dlo[ft], 0, 0, 0);
        dhi[ft] = __builtin_amdgcn_mfma_f32_16x16x32_bf16(ahi, pb[ft][ks], dhi[ft], 0, 0, 0);
      }
    }
    if (lane < 8) {
      int row = w*8 + lane;
      float s = 0.f;
      #pragma unroll
      for (int c = 0; c < 8; ++c) s += red[row][c];
      diag_s[row] = 0.5f*s;
    }
    __syncthreads();
    // ---- exp, mask, write E^T ----
    #pragma unroll
    for (int ft = 0; ft < 4; ++ft) {
      int f = w*64 + ft*16 + fcol;
      unsigned short us[4];
      #pragma unroll
      for (int j = 0; j < 4; ++j) {
        int n = g4 + j;
        float x = dlo[ft][j];
        maxd = fmaxf(maxd, x);
        float E = (mtile_s[n] != 0.f) ? __expf(x - diag_s[n]) : 0.f;
        ksum_p[ft] += E;
        us[j] = f2bs(E);
      }
      *(unsigned int*)&eT[f][g4]   = (unsigned int)us[0] | ((unsigned int)us[1] << 16);
      *(unsigned int*)&eT[f][g4+2] = (unsigned int)us[2] | ((unsigned int)us[3] << 16);
      #pragma unroll
      for (int j = 0; j < 4; ++j) {
        int n = 16 + g4 + j;
        float x = dhi[ft][j];
        maxd = fmaxf(maxd, x);
        float E = (mtile_s[n] != 0.f) ? __expf(x - diag_s[n]) : 0.f;
        ksum_p[ft] += E;
        us[j] = f2bs(E);
      }
      *(unsigned int*)&eT[f][16+g4]   = (unsigned int)us[0] | ((unsigned int)us[1] << 16);
      *(unsigned int*)&eT[f][16+g4+2] = (unsigned int)us[2] | ((unsigned int)us[3] << 16);
    }
    __syncthreads();
    // ---- ctx MFMAs: ctx[f][e] += E^T * V ----
    {
      short8v av[4];
      #pragma unroll
      for (int ft = 0; ft < 4; ++ft)
        av[ft] = *(const short8v*)&eT[w*64 + ft*16 + fcol][g*8];
      #pragma unroll
      for (int et = 0; et < 4; ++et) {
        short8v bv = *(const short8v*)&vtT[et*16 + fcol][g*8];
        #pragma unroll
        for (int ft = 0; ft < 4; ++ft)
          ctx[ft][et] = __builtin_amdgcn_mfma_f32_16x16x32_bf16(av[ft], bv, ctx[ft][et], 0, 0, 0);
      }
    }
    // ---- vs / nm ----
    if (tid < 64) {
      #pragma unroll 1
      for (int rr = 0; rr < 32; ++rr)
        if (mtile_s[rr] != 0.f) vs += bs2f(vtT[tid][rr]);
    }
    if (tid == 0) {
      for (int rr = 0; rr < 32; ++rr) nm += mtile_s[rr];
    }
  }

  // ---- epilogue ----
  #pragma unroll
  for (int ft = 0; ft < 4; ++ft) {
    float k0 = ksum_p[ft];
    k0 += __shfl_xor(k0, 16);
    k0 += __shfl_xor(k0, 32);
    if (g == 0)
      atomicAdd(&W[OFF_KSUM + bh*256 + w*64 + ft*16 + fcol], k0);
  }
  #pragma unroll
  for (int ft = 0; ft < 4; ++ft)
    #pragma unroll
    for (int et = 0; et < 4; ++et)
      #pragma unroll
      for (int j = 0; j < 4; ++j) {
        int f = w*64 + ft*16 + g4 + j;
        int e = et*16 + fcol;
        atomicAdd(&W[OFF_CTX + (size_t)bh*16384 + f*64 + e], ctx[ft][et][j]);
      }
  if (tid < 64) atomicAdd(&W[OFF_VSUM + bh*64 + tid], vs);
  if (tid == 0) atomicAdd(&W[OFF_NMASK + bh], nm);
  mred[tid] = maxd;
  __syncthreads();
  for (int s = 128; s > 0; s >>= 1) {
    if (tid < s) mred[tid] = fmaxf(mred[tid], mred[tid+s]);
    __syncthreads();
  }
  if (tid == 0) W[OFF_BMAX + blockIdx.x] = mred[0];
}

__global__ void k_mkred(float* __restrict__ W) {
  int i = threadIdx.x;
  if (i < 32) {
    float m = -INFINITY;
    for (int c = 0; c < NCH; ++c) m = fmaxf(m, W[OFF_BMAX + i*NCH + c]);
    W[OFF_MK + i] = m;
  }
}

__global__ __launch_bounds__(256)
void k_finalize(float* __restrict__ W) {
  int bh = blockIdx.x;
  int tid = threadIdx.x;
  float emk  = RATIO * expf(-W[OFF_MK + bh]);
  float epsr = RATIO * SM_EPS;
  float nm = W[OFF_NMASK + bh];
  {
    float* ks = &W[OFF_KSUM + bh*256];
    ks[tid] = emk*ks[tid] + epsr*nm;
  }
  float* ctx = &W[OFF_CTX + (size_t)bh*16384];
  const float* vsum = &W[OFF_VSUM + bh*64];
  for (int i = tid; i < 16384; i += 256) {
    int e = i & 63;
    ctx[i] = emk*ctx[i] + epsr*vsum[e];
  }
}

__global__ __launch_bounds__(256)
void k_pass2(const float* __restrict__ query, const float* __restrict__ coords,
             const float* __restrict__ omR_g, const float* __restrict__ omA_g,
             const float* __restrict__ outb, const float* __restrict__ W,
             float* __restrict__ out) {
  int b  = blockIdx.x >> 9;
  int n0 = (blockIdx.x & 511) * 16;
  int tid = threadIdx.x;
  __shared__ __align__(16) float kc[16][192];
  __shared__ __align__(16) float qp[16][256];
  __shared__ __align__(16) float attn[16][64];
  __shared__ float ksl[256];
  __shared__ float sxyz[16][3];
  __shared__ float diag[16];
  __shared__ float mq[16];
  __shared__ float dnm[16];
  __shared__ float red[16][16];
  __shared__ float omR[64], omA[32];

  if (tid < 64) omR[tid] = omR_g[tid];
  if (tid < 32) omA[tid] = omA_g[tid];

  int r = tid >> 4, l = tid & 15;
  int rg = tid >> 6, e = tid & 63;
  float facc[4] = {0.f, 0.f, 0.f, 0.f};

  for (int h = 0; h < 8; ++h) {
    int bh = b*8 + h;
    float s0 = W[OFF_CONST + h*8 + 0];
    float s1 = W[OFF_CONST + h*8 + 1];
    float s2 = W[OFF_CONST + h*8 + 2];
    float a0 = W[OFF_CONST + h*8 + 3] * RFF_S;
    float a1 = W[OFF_CONST + h*8 + 4] * RFF_S;
    __syncthreads();
    ksl[tid] = W[OFF_KSUM + bh*256 + tid];
    {
      int n = n0 + r;
      const float* qpr = query + ((size_t)b*N_ + n)*512 + h*64 + l*4;
      float4 qv = *(const float4*)qpr;
      kc[r][l*4+0] = qv.x*SQT; kc[r][l*4+1] = qv.y*SQT;
      kc[r][l*4+2] = qv.z*SQT; kc[r][l*4+3] = qv.w*SQT;
      if (l == 0) {
        const float* cp = coords + ((size_t)b*N_ + n)*3;
        sxyz[r][0] = cp[0]*s0; sxyz[r][1] = cp[1]*s1; sxyz[r][2] = cp[2]*s2;
      }
    }
    __syncthreads();
    {
      float px = sxyz[r][0], py = sxyz[r][1], pz = sxyz[r][2];
      #pragma unroll
      for (int i = 0; i < 4; ++i) {
        int idx = l + 16*i;
        if (idx < 32) {
          float u = px*omR[idx] + py*omR[32+idx];
          float sn, cs; __sincosf(u, &sn, &cs);
          kc[r][64+idx] = cs*a0; kc[r][96+idx] = sn*a0;
        } else {
          int j = idx - 32;
          float u = pz*omA[j];
          float sn, cs; __sincosf(u, &sn, &cs);
          kc[r][128+j] = cs*a1; kc[r][160+j] = sn*a1;
        }
      }
    }
    __syncthreads();
    {
      float s = 0.f;
      #pragma unroll
      for (int i = 0; i < 12; ++i) { float v = kc[r][l*12+i]; s += v*v; }
      red[r][l] = s;
    }
    __syncthreads();
    if (l == 0) {
      float s = 0.f;
      #pragma unroll
      for (int i = 0; i < 16; ++i) s += red[r][i];
      diag[r] = 0.5f*s;
    }
    __syncthreads();
    float dash[16];
    #pragma unroll
    for (int rr = 0; rr < 16; ++rr) dash[rr] = 0.f;
    const float4* pT = (const float4*)&W[OFF_PROJT];
    for (int dq = 0; dq < 48; ++dq) {
      float4 p = pT[dq*256 + tid];
      #pragma unroll
      for (int rr = 0; rr < 16; ++rr) {
        float4 c = *(const float4*)&kc[rr][dq*4];
        dash[rr] = fmaf(p.x, c.x, fmaf(p.y, c.y, fmaf(p.z, c.z, fmaf(p.w, c.w, dash[rr]))));
      }
    }
    #pragma unroll
    for (int rr = 0; rr < 16; ++rr) qp[rr][tid] = dash[rr];
    __syncthreads();
    {
      float m = -INFINITY;
      for (int fi = l; fi < 256; fi += 16) m = fmaxf(m, qp[r][fi]);
      red[r][l] = m;
    }
    __syncthreads();
    if (l == 0) {
      float m = -INFINITY;
      #pragma unroll
      for (int i = 0; i < 16; ++i) m = fmaxf(m, red[r][i]);
      mq[r] = m;
    }
    __syncthreads();
    #pragma unroll
    for (int rr = 0; rr < 16; ++rr) {
      float qv = RATIO * (__expf(qp[rr][tid] - diag[rr] - mq[rr]) + SM_EPS);
      qp[rr][tid] = qv;
    }
    __syncthreads();
    {
      float s = 0.f;
      for (int fi = l; fi < 256; fi += 16) s += qp[r][fi] * ksl[fi];
      red[r][l] = s;
    }
    __syncthreads();
    if (l == 0) {
      float s = 0.f;
      #pragma unroll
      for (int i = 0; i < 16; ++i) s += red[r][i];
      dnm[r] = 1.f / (s + NORM_EPS);
    }
    __syncthreads();
    {
      const float* ctxg = &W[OFF_CTX + (size_t)bh*16384];
      float acc[4] = {0.f, 0.f, 0.f, 0.f};
      for (int fi = 0; fi < 256; ++fi) {
        float cx = ctxg[fi*64 + e];
        #pragma unroll
        for (int i = 0; i < 4; ++i) acc[i] = fmaf(qp[rg*4+i][fi], cx, acc[i]);
      }
      #pragma unroll
      for (int i = 0; i < 4; ++i) attn[rg*4+i][e] = acc[i] * dnm[rg*4+i];
    }
    __syncthreads();
    {
      const float* owT = &W[OFF_OWT + h*64*64];
      #pragma unroll 1
      for (int ee = 0; ee < 64; ++ee) {
        float wv = owT[ee*64 + e];
        #pragma unroll
        for (int i = 0; i < 4; ++i) facc[i] = fmaf(attn[rg*4+i][ee], wv, facc[i]);
      }
    }
  }
  {
    float bj = outb[e];
    #pragma unroll
    for (int i = 0; i < 4; ++i) {
      int n = n0 + rg*4 + i;
      out[((size_t)b*N_ + n)*64 + e] = facc[i] + bj;
    }
  }
}

extern "C" void kernel_launch(void* const* d_in, const int* in_sizes, int n_in,
                              void* d_out, int out_size, void* d_ws, size_t ws_size,
                              hipStream_t stream) {
  const float* query  = (const float*)d_in[0];
  const float* key    = (const float*)d_in[1];
  const float* value  = (const float*)d_in[2];
  const float* coords = (const float*)d_in[3];
  const void*  mask   = d_in[4];
  const float* wrpe   = (const float*)d_in[5];
  const float* omR    = (const float*)d_in[6];
  const float* omA    = (const float*)d_in[7];
  const float* proj   = (const float*)d_in[8];
  const float* outw   = (const float*)d_in[9];
  const float* outb   = (const float*)d_in[10];
  float* W = (float*)d_ws;
  float* out = (float*)d_out;

  hipMemsetAsync(W + ZERO_BEG, 0, (size_t)(ZERO_END - ZERO_BEG)*sizeof(float), stream);
  hipLaunchKernelGGL(k_consts,   dim3(1),        dim3(256), 0, stream, wrpe, proj, outw,
                     (const unsigned int*)mask, W);
  hipLaunchKernelGGL(k_pass1,    dim3(32*NCH),   dim3(256), 0, stream, key, value, coords, mask,
                     omR, omA, proj, W);
  hipLaunchKernelGGL(k_mkred,    dim3(1),        dim3(64),  0, stream, W);
  hipLaunchKernelGGL(k_finalize, dim3(32),       dim3(256), 0, stream, W);
  hipLaunchKernelGGL(k_pass2,    dim3(2048),     dim3(256), 0, stream, query, coords, omR, omA, outb, W, out);
}

// Round 9
// 385.286 us; speedup vs baseline: 8.0551x; 3.0589x over previous
//
#include <hip/hip_runtime.h>
#include <hip/hip_bf16.h>
#include <math.h>

constexpr int B_ = 4, N_ = 8192, H_ = 8;
constexpr float SQT    = 0.35355339059327373f;   // sqrt(SOFTMAX_TEMP)
constexpr float RFF_S  = 0.17677669529663687f;   // sqrt(2/64)
constexpr float RATIO  = 0.0625f;                // 256^-0.5
constexpr float SM_EPS = 1e-6f;
constexpr float NORM_EPS = 1e-6f;

constexpr int NCH = 16, CHUNK = N_ / NCH;        // pass1: 512 rows/block, grid 512

// ws layout (float offsets)
constexpr int OFF_CONST = 0;
constexpr int OFF_FLAG  = 63;
constexpr int OFF_MK    = 64;
constexpr int OFF_NMASK = 96;
constexpr int OFF_KSUM  = 128;      // 32*256
constexpr int OFF_VSUM  = 8320;     // 32*64
constexpr int OFF_BMAX  = 10368;    // 512
constexpr int OFF_CTX   = 10880;    // 32*256*64 f32; finalize converts in-place to bf16 ctxT[bh][64][256]
constexpr int OFF_OWB   = 535168;   // 64*512 bf16 out_w (32768 shorts = 16384 float-slots)
constexpr int ZERO_BEG  = OFF_NMASK;
constexpr int ZERO_END  = OFF_CTX + 32*16384;

typedef __attribute__((ext_vector_type(8))) short short8v;
typedef __attribute__((ext_vector_type(4))) float f32x4;

__device__ __forceinline__ unsigned short f2bs(float x) {
  union { float f; unsigned int u; } v; v.f = x;
  unsigned int r = v.u + 0x7fffu + ((v.u >> 16) & 1u);
  return (unsigned short)(r >> 16);
}
__device__ __forceinline__ float bs2f(unsigned short s) {
  union { unsigned int u; float f; } v; v.u = ((unsigned int)s) << 16;
  return v.f;
}

__global__ __launch_bounds__(256)
void k_consts(const float* __restrict__ wrpe, const float* __restrict__ outw,
              const unsigned int* __restrict__ maskw, float* __restrict__ W) {
  __shared__ float exs[128];
  __shared__ float qwv[8][2];
  __shared__ int f_gt1, f_oddnz, f_evennz;
  int tid = threadIdx.x;
  if (tid == 0) { f_gt1 = 0; f_oddnz = 0; f_evennz = 0; }
  __syncthreads();
  {
    int gt1 = 0, oddnz = 0, evennz = 0;
    for (int i = tid; i < 8192; i += 256) {
      unsigned int v = maskw[i];
      if (v > 1u) gt1 = 1;
      if (v != 0u) { if (i & 1) oddnz = 1; else evennz = 1; }
    }
    if (gt1)    atomicOr(&f_gt1, 1);
    if (oddnz)  atomicOr(&f_oddnz, 1);
    if (evennz) atomicOr(&f_evennz, 1);
  }
  if (tid < 128) {
    int h = tid >> 4, r = (tid >> 3) & 1, c = (tid >> 2) & 1, k = tid & 3;
    float s = 0.f;
    for (int d = 0; d < 64; ++d) s += wrpe[(h*64 + d)*16 + r*8 + c*4 + k];
    exs[tid] = expf(fminf(s, 50.f));
  }
  __syncthreads();
  if (tid == 0) {
    float flag = 0.f;
    if (f_gt1) flag = 1.f;
    else if (!f_oddnz && f_evennz) flag = 2.f;
    W[OFF_FLAG] = flag;
  }
  if (tid < 32) {
    int h = tid >> 2, r = (tid >> 1) & 1, c = tid & 1;
    float s = 0.f;
    for (int k = 0; k < 4; ++k) s += exs[h*16 + r*8 + c*4 + k];
    if (c == 0) W[OFF_CONST + h*8 + 3 + r] = sqrtf(s);
    else        qwv[h][r] = s;
  }
  __syncthreads();
  if (tid < 8) {
    int h = tid;
    float s0 = sqrtf(qwv[h][0]), s1 = sqrtf(qwv[h][1]);
    W[OFF_CONST + h*8 + 0] = s0;
    W[OFF_CONST + h*8 + 1] = s0;
    W[OFF_CONST + h*8 + 2] = s1;
  }
  for (int i = tid; i < 32*NCH; i += 256) W[OFF_BMAX + i] = -INFINITY;
  // out_w -> bf16, layout unchanged [j][c]
  unsigned short* owb = (unsigned short*)&W[OFF_OWB];
  for (int i = tid; i < 64*512; i += 256) owb[i] = f2bs(outw[i]);
}

__device__ __forceinline__ int read_mask(const void* maskp, int mtype, size_t idx) {
  if (mtype == 1) return (int)((const unsigned char*)maskp)[idx];
  if (mtype == 2) return (int)((const long long*)maskp)[idx];
  return ((const int*)maskp)[idx];
}

__global__ __launch_bounds__(256, 2)
void k_pass1(const float* __restrict__ key, const float* __restrict__ value,
             const float* __restrict__ coords, const void* __restrict__ maskp,
             const float* __restrict__ omR_g, const float* __restrict__ omA_g,
             const float* __restrict__ proj, float* __restrict__ W) {
  int bh = blockIdx.x / NCH, ch = blockIdx.x % NCH;
  int b = bh >> 3, h = bh & 7;
  int tid = threadIdx.x;
  int w = tid >> 6, lane = tid & 63, g = lane >> 4, fcol = lane & 15, g4 = g*4;

  __shared__ __align__(16) unsigned short kcb[32][200];
  __shared__ __align__(16) unsigned short vtT[64][40];
  __shared__ __align__(16) unsigned short eT[256][40];
  __shared__ float red[32][8];
  __shared__ float diag_s[32];
  __shared__ float mtile_s[32];
  __shared__ float mred[256];
  __shared__ float omR[64], omA[32];

  if (tid < 64) omR[tid] = omR_g[tid];
  if (tid < 32) omA[tid] = omA_g[tid];
  int mtype = (int)W[OFF_FLAG];
  float s0 = W[OFF_CONST + h*8 + 0];
  float s1 = W[OFF_CONST + h*8 + 1];
  float s2 = W[OFF_CONST + h*8 + 2];
  float a0 = W[OFF_CONST + h*8 + 3] * RFF_S;
  float a1 = W[OFF_CONST + h*8 + 4] * RFF_S;

  short8v pb[4][6];
  #pragma unroll
  for (int ft = 0; ft < 4; ++ft) {
    int f = w*64 + ft*16 + fcol;
    #pragma unroll
    for (int ks = 0; ks < 6; ++ks) {
      const float* p = proj + (size_t)f*192 + ks*32 + g*8;
      float4 p0 = *(const float4*)p;
      float4 p1 = *(const float4*)(p + 4);
      short8v v;
      v[0]=f2bs(p0.x); v[1]=f2bs(p0.y); v[2]=f2bs(p0.z); v[3]=f2bs(p0.w);
      v[4]=f2bs(p1.x); v[5]=f2bs(p1.y); v[6]=f2bs(p1.z); v[7]=f2bs(p1.w);
      pb[ft][ks] = v;
    }
  }

  f32x4 ctx[4][4];
  #pragma unroll
  for (int i = 0; i < 4; ++i)
    #pragma unroll
    for (int j = 0; j < 4; ++j) ctx[i][j] = (f32x4){0.f,0.f,0.f,0.f};
  float ksum_p[4] = {0.f,0.f,0.f,0.f};
  float maxd = -INFINITY, vs = 0.f, nm = 0.f;

  int srow = tid >> 3, sc = tid & 7;

  for (int t = 0; t < CHUNK/32; ++t) {
    int n0 = ch*CHUNK + t*32;
    __syncthreads();
    {
      size_t nidx = (size_t)b*N_ + n0 + srow;
      const float* kp = key + nidx*512 + h*64 + sc*8;
      const float* vp = value + nidx*512 + h*64 + sc*8;
      float4 k0 = *(const float4*)kp, k1 = *(const float4*)(kp+4);
      float4 v0 = *(const float4*)vp, v1 = *(const float4*)(vp+4);
      float kk[8] = {k0.x*SQT,k0.y*SQT,k0.z*SQT,k0.w*SQT,k1.x*SQT,k1.y*SQT,k1.z*SQT,k1.w*SQT};
      float sq = 0.f;
      short8v kv;
      #pragma unroll
      for (int i = 0; i < 8; ++i) { sq += kk[i]*kk[i]; kv[i] = f2bs(kk[i]); }
      *(short8v*)&kcb[srow][sc*8] = kv;
      float vv[8] = {v0.x,v0.y,v0.z,v0.w,v1.x,v1.y,v1.z,v1.w};
      #pragma unroll
      for (int i = 0; i < 8; ++i) vtT[sc*8+i][srow] = f2bs(vv[i]);
      const float* cp = coords + nidx*3;
      float px = cp[0]*s0, py = cp[1]*s1, pz = cp[2]*s2;
      #pragma unroll
      for (int ii = 0; ii < 8; ++ii) {
        int idx = sc*8 + ii;
        float sn, cs;
        if (idx < 32) {
          float u = px*omR[idx] + py*omR[32+idx];
          __sincosf(u, &sn, &cs);
          float cv = cs*a0, sv = sn*a0;
          kcb[srow][64+idx] = f2bs(cv); kcb[srow][96+idx] = f2bs(sv);
          sq += cv*cv + sv*sv;
        } else {
          int j = idx - 32;
          float u = pz*omA[j];
          __sincosf(u, &sn, &cs);
          float cv = cs*a1, sv = sn*a1;
          kcb[srow][128+j] = f2bs(cv); kcb[srow][160+j] = f2bs(sv);
          sq += cv*cv + sv*sv;
        }
      }
      red[srow][sc] = sq;
      if (tid < 32)
        mtile_s[tid] = (read_mask(maskp, mtype, (size_t)b*N_ + n0 + tid) != 0) ? 1.f : 0.f;
    }
    __syncthreads();
    f32x4 dlo[4], dhi[4];
    #pragma unroll
    for (int ft = 0; ft < 4; ++ft) { dlo[ft] = (f32x4){0,0,0,0}; dhi[ft] = (f32x4){0,0,0,0}; }
    #pragma unroll
    for (int ks = 0; ks < 6; ++ks) {
      short8v alo = *(const short8v*)&kcb[fcol][ks*32 + g*8];
      short8v ahi = *(const short8v*)&kcb[16+fcol][ks*32 + g*8];
      #pragma unroll
      for (int ft = 0; ft < 4; ++ft) {
        dlo[ft] = __builtin_amdgcn_mfma_f32_16x16x32_bf16(alo, pb[ft][ks], dlo[ft], 0, 0, 0);
        dhi[ft] = __builtin_amdgcn_mfma_f32_16x16x32_bf16(ahi, pb[ft][ks], dhi[ft], 0, 0, 0);
      }
    }
    if (lane < 8) {
      int row = w*8 + lane;
      float s = 0.f;
      #pragma unroll
      for (int c = 0; c < 8; ++c) s += red[row][c];
      diag_s[row] = 0.5f*s;
    }
    __syncthreads();
    #pragma unroll
    for (int ft = 0; ft < 4; ++ft) {
      int f = w*64 + ft*16 + fcol;
      unsigned short us[4];
      #pragma unroll
      for (int j = 0; j < 4; ++j) {
        int n = g4 + j;
        float x = dlo[ft][j];
        maxd = fmaxf(maxd, x);
        float E = (mtile_s[n] != 0.f) ? __expf(x - diag_s[n]) : 0.f;
        ksum_p[ft] += E;
        us[j] = f2bs(E);
      }
      *(unsigned int*)&eT[f][g4]   = (unsigned int)us[0] | ((unsigned int)us[1] << 16);
      *(unsigned int*)&eT[f][g4+2] = (unsigned int)us[2] | ((unsigned int)us[3] << 16);
      #pragma unroll
      for (int j = 0; j < 4; ++j) {
        int n = 16 + g4 + j;
        float x = dhi[ft][j];
        maxd = fmaxf(maxd, x);
        float E = (mtile_s[n] != 0.f) ? __expf(x - diag_s[n]) : 0.f;
        ksum_p[ft] += E;
        us[j] = f2bs(E);
      }
      *(unsigned int*)&eT[f][16+g4]   = (unsigned int)us[0] | ((unsigned int)us[1] << 16);
      *(unsigned int*)&eT[f][16+g4+2] = (unsigned int)us[2] | ((unsigned int)us[3] << 16);
    }
    __syncthreads();
    {
      short8v av[4];
      #pragma unroll
      for (int ft = 0; ft < 4; ++ft)
        av[ft] = *(const short8v*)&eT[w*64 + ft*16 + fcol][g*8];
      #pragma unroll
      for (int et = 0; et < 4; ++et) {
        short8v bv = *(const short8v*)&vtT[et*16 + fcol][g*8];
        #pragma unroll
        for (int ft = 0; ft < 4; ++ft)
          ctx[ft][et] = __builtin_amdgcn_mfma_f32_16x16x32_bf16(av[ft], bv, ctx[ft][et], 0, 0, 0);
      }
    }
    if (tid < 64) {
      #pragma unroll 1
      for (int rr = 0; rr < 32; ++rr)
        if (mtile_s[rr] != 0.f) vs += bs2f(vtT[tid][rr]);
    }
    if (tid == 0) {
      for (int rr = 0; rr < 32; ++rr) nm += mtile_s[rr];
    }
  }

  #pragma unroll
  for (int ft = 0; ft < 4; ++ft) {
    float k0 = ksum_p[ft];
    k0 += __shfl_xor(k0, 16);
    k0 += __shfl_xor(k0, 32);
    if (g == 0)
      atomicAdd(&W[OFF_KSUM + bh*256 + w*64 + ft*16 + fcol], k0);
  }
  #pragma unroll
  for (int ft = 0; ft < 4; ++ft)
    #pragma unroll
    for (int et = 0; et < 4; ++et)
      #pragma unroll
      for (int j = 0; j < 4; ++j) {
        int f = w*64 + ft*16 + g4 + j;
        int e = et*16 + fcol;
        atomicAdd(&W[OFF_CTX + (size_t)bh*16384 + f*64 + e], ctx[ft][et][j]);
      }
  if (tid < 64) atomicAdd(&W[OFF_VSUM + bh*64 + tid], vs);
  if (tid == 0) atomicAdd(&W[OFF_NMASK + bh], nm);
  mred[tid] = maxd;
  __syncthreads();
  for (int s = 128; s > 0; s >>= 1) {
    if (tid < s) mred[tid] = fmaxf(mred[tid], mred[tid+s]);
    __syncthreads();
  }
  if (tid == 0) W[OFF_BMAX + blockIdx.x] = mred[0];
}

__global__ void k_mkred(float* __restrict__ W) {
  int i = threadIdx.x;
  if (i < 32) {
    float m = -INFINITY;
    for (int c = 0; c < NCH; ++c) m = fmaxf(m, W[OFF_BMAX + i*NCH + c]);
    W[OFF_MK + i] = m;
  }
}

// scale ksum/ctx, then convert ctx in-place to bf16 ctxT[e][f] (buffered via LDS)
__global__ __launch_bounds__(256)
void k_finalize(float* __restrict__ W) {
  __shared__ float buf[16384];
  int bh = blockIdx.x;
  int tid = threadIdx.x;
  float emk  = RATIO * __expf(-W[OFF_MK + bh]);
  float epsr = RATIO * SM_EPS;
  float nm = W[OFF_NMASK + bh];
  W[OFF_KSUM + bh*256 + tid] = emk*W[OFF_KSUM + bh*256 + tid] + epsr*nm;
  float* ctx = &W[OFF_CTX + (size_t)bh*16384];
  const float* vsum = &W[OFF_VSUM + bh*64];
  for (int i = tid; i < 16384; i += 256) {
    int e = i & 63;
    buf[i] = emk*ctx[i] + epsr*vsum[e];
  }
  __syncthreads();
  unsigned short* ct = (unsigned short*)ctx;
  for (int i = tid; i < 16384; i += 256) {
    int e = i >> 8, f = i & 255;
    ct[i] = f2bs(buf[f*64 + e]);
  }
}

__global__ __launch_bounds__(256, 2)
void k_pass2(const float* __restrict__ query, const float* __restrict__ coords,
             const float* __restrict__ omR_g, const float* __restrict__ omA_g,
             const float* __restrict__ proj, const float* __restrict__ outb,
             float* __restrict__ W, float* __restrict__ out) {
  int b  = blockIdx.x >> 8;          // N/32 = 256 tiles per batch
  int n0 = (blockIdx.x & 255) * 32;
  int tid = threadIdx.x;
  int w = tid >> 6, lane = tid & 63, g = lane >> 4, fcol = lane & 15, g4 = g*4;

  __shared__ __align__(16) unsigned short kcb[32][200];
  __shared__ __align__(16) unsigned short qpE[32][280];
  __shared__ __align__(16) unsigned short attnb[32][72];
  __shared__ float red[32][8];
  __shared__ float diag_s[32];
  __shared__ float mredw[4][32];
  __shared__ float red2[4][32];
  __shared__ float mq[32];
  __shared__ float dnm[32];
  __shared__ float ksl[256];
  __shared__ float omR[64], omA[32];

  if (tid < 64) omR[tid] = omR_g[tid];
  if (tid < 32) omA[tid] = omA_g[tid];

  short8v pb[4][6];
  #pragma unroll
  for (int ft = 0; ft < 4; ++ft) {
    int f = w*64 + ft*16 + fcol;
    #pragma unroll
    for (int ks = 0; ks < 6; ++ks) {
      const float* p = proj + (size_t)f*192 + ks*32 + g*8;
      float4 p0 = *(const float4*)p;
      float4 p1 = *(const float4*)(p + 4);
      short8v v;
      v[0]=f2bs(p0.x); v[1]=f2bs(p0.y); v[2]=f2bs(p0.z); v[3]=f2bs(p0.w);
      v[4]=f2bs(p1.x); v[5]=f2bs(p1.y); v[6]=f2bs(p1.z); v[7]=f2bs(p1.w);
      pb[ft][ks] = v;
    }
  }

  const unsigned short* owb = (const unsigned short*)&W[OFF_OWB];
  int srow = tid >> 3, sc = tid & 7;
  f32x4 oacc[2];
  oacc[0] = (f32x4){0,0,0,0}; oacc[1] = (f32x4){0,0,0,0};

  for (int h = 0; h < 8; ++h) {
    int bh = b*8 + h;
    float s0 = W[OFF_CONST + h*8 + 0];
    float s1 = W[OFF_CONST + h*8 + 1];
    float s2 = W[OFF_CONST + h*8 + 2];
    float a0 = W[OFF_CONST + h*8 + 3] * RFF_S;
    float a1 = W[OFF_CONST + h*8 + 4] * RFF_S;
    __syncthreads();   // protect kcb/qpE/attnb from previous iteration readers
    ksl[tid] = W[OFF_KSUM + bh*256 + tid];
    {
      size_t nidx = (size_t)b*N_ + n0 + srow;
      const float* qp_ = query + nidx*512 + h*64 + sc*8;
      float4 q0 = *(const float4*)qp_, q1 = *(const float4*)(qp_+4);
      float kk[8] = {q0.x*SQT,q0.y*SQT,q0.z*SQT,q0.w*SQT,q1.x*SQT,q1.y*SQT,q1.z*SQT,q1.w*SQT};
      float sq = 0.f;
      short8v kv;
      #pragma unroll
      for (int i = 0; i < 8; ++i) { sq += kk[i]*kk[i]; kv[i] = f2bs(kk[i]); }
      *(short8v*)&kcb[srow][sc*8] = kv;
      const float* cp = coords + nidx*3;
      float px = cp[0]*s0, py = cp[1]*s1, pz = cp[2]*s2;
      #pragma unroll
      for (int ii = 0; ii < 8; ++ii) {
        int idx = sc*8 + ii;
        float sn, cs;
        if (idx < 32) {
          float u = px*omR[idx] + py*omR[32+idx];
          __sincosf(u, &sn, &cs);
          float cv = cs*a0, sv = sn*a0;
          kcb[srow][64+idx] = f2bs(cv); kcb[srow][96+idx] = f2bs(sv);
          sq += cv*cv + sv*sv;
        } else {
          int j = idx - 32;
          float u = pz*omA[j];
          __sincosf(u, &sn, &cs);
          float cv = cs*a1, sv = sn*a1;
          kcb[srow][128+j] = f2bs(cv); kcb[srow][160+j] = f2bs(sv);
          sq += cv*cv + sv*sv;
        }
      }
      red[srow][sc] = sq;
    }
    __syncthreads();
    if (lane < 8) {
      int row = w*8 + lane;
      float s = 0.f;
      #pragma unroll
      for (int c = 0; c < 8; ++c) s += red[row][c];
      diag_s[row] = 0.5f*s;
    }
    // dash MFMAs
    f32x4 dlo[4], dhi[4];
    #pragma unroll
    for (int ft = 0; ft < 4; ++ft) { dlo[ft] = (f32x4){0,0,0,0}; dhi[ft] = (f32x4){0,0,0,0}; }
    #pragma unroll
    for (int ks = 0; ks < 6; ++ks) {
      short8v alo = *(const short8v*)&kcb[fcol][ks*32 + g*8];
      short8v ahi = *(const short8v*)&kcb[16+fcol][ks*32 + g*8];
      #pragma unroll
      for (int ft = 0; ft < 4; ++ft) {
        dlo[ft] = __builtin_amdgcn_mfma_f32_16x16x32_bf16(alo, pb[ft][ks], dlo[ft], 0, 0, 0);
        dhi[ft] = __builtin_amdgcn_mfma_f32_16x16x32_bf16(ahi, pb[ft][ks], dhi[ft], 0, 0, 0);
      }
    }
    // row max over f
    {
      float ml[4], mh[4];
      #pragma unroll
      for (int j = 0; j < 4; ++j) {
        ml[j] = fmaxf(fmaxf(dlo[0][j], dlo[1][j]), fmaxf(dlo[2][j], dlo[3][j]));
        mh[j] = fmaxf(fmaxf(dhi[0][j], dhi[1][j]), fmaxf(dhi[2][j], dhi[3][j]));
      }
      #pragma unroll
      for (int m = 1; m <= 8; m <<= 1) {
        #pragma unroll
        for (int j = 0; j < 4; ++j) {
          ml[j] = fmaxf(ml[j], __shfl_xor(ml[j], m));
          mh[j] = fmaxf(mh[j], __shfl_xor(mh[j], m));
        }
      }
      if (fcol == 0) {
        #pragma unroll
        for (int j = 0; j < 4; ++j) {
          mredw[w][g4+j] = ml[j];
          mredw[w][16+g4+j] = mh[j];
        }
      }
    }
    __syncthreads();
    if (tid < 32)
      mq[tid] = fmaxf(fmaxf(mredw[0][tid], mredw[1][tid]), fmaxf(mredw[2][tid], mredw[3][tid]));
    __syncthreads();
    // E = RATIO*(exp(dash-diag-mq)+eps); den partials; write qpE bf16 (unscaled)
    {
      float dp[8] = {0,0,0,0,0,0,0,0};
      #pragma unroll
      for (int ft = 0; ft < 4; ++ft) {
        int f = w*64 + ft*16 + fcol;
        float kf = ksl[f];
        #pragma unroll
        for (int j = 0; j < 4; ++j) {
          int n = g4 + j;
          float Ex = RATIO * (__expf(dlo[ft][j] - diag_s[n] - mq[n]) + SM_EPS);
          dp[j] += Ex * kf;
          qpE[n][f] = f2bs(Ex);
          int n2 = 16 + g4 + j;
          float Ex2 = RATIO * (__expf(dhi[ft][j] - diag_s[n2] - mq[n2]) + SM_EPS);
          dp[4+j] += Ex2 * kf;
          qpE[n2][f] = f2bs(Ex2);
        }
      }
      #pragma unroll
      for (int m = 1; m <= 8; m <<= 1)
        #pragma unroll
        for (int s = 0; s < 8; ++s) dp[s] += __shfl_xor(dp[s], m);
      if (fcol == 0) {
        #pragma unroll
        for (int j = 0; j < 4; ++j) {
          red2[w][g4+j] = dp[j];
          red2[w][16+g4+j] = dp[4+j];
        }
      }
    }
    __syncthreads();
    if (tid < 32)
      dnm[tid] = 1.f / (red2[0][tid] + red2[1][tid] + red2[2][tid] + red2[3][tid] + NORM_EPS);
    __syncthreads();
    // attn MFMA: pa[rt] = qpE(32x256) . ctxT  (wave w -> e cols w*16..+15)
    {
      const unsigned short* ct = (const unsigned short*)&W[OFF_CTX + (size_t)bh*16384];
      int e = w*16 + fcol;
      f32x4 pa[2];
      pa[0] = (f32x4){0,0,0,0}; pa[1] = (f32x4){0,0,0,0};
      #pragma unroll
      for (int ks = 0; ks < 8; ++ks) {
        short8v bv = *(const short8v*)&ct[e*256 + ks*32 + g*8];
        short8v a0v = *(const short8v*)&qpE[fcol][ks*32 + g*8];
        short8v a1v = *(const short8v*)&qpE[16+fcol][ks*32 + g*8];
        pa[0] = __builtin_amdgcn_mfma_f32_16x16x32_bf16(a0v, bv, pa[0], 0, 0, 0);
        pa[1] = __builtin_amdgcn_mfma_f32_16x16x32_bf16(a1v, bv, pa[1], 0, 0, 0);
      }
      #pragma unroll
      for (int rt = 0; rt < 2; ++rt)
        #pragma unroll
        for (int j = 0; j < 4; ++j) {
          int n = rt*16 + g4 + j;
          attnb[n][e] = f2bs(pa[rt][j] * dnm[n]);
        }
    }
    __syncthreads();
    // out-proj MFMA accumulate over h (wave w -> out cols w*16..+15)
    {
      #pragma unroll
      for (int ks2 = 0; ks2 < 2; ++ks2) {
        short8v bo = *(const short8v*)&owb[(size_t)(w*16 + fcol)*512 + h*64 + ks2*32 + g*8];
        short8v aa0 = *(const short8v*)&attnb[fcol][ks2*32 + g*8];
        short8v aa1 = *(const short8v*)&attnb[16+fcol][ks2*32 + g*8];
        oacc[0] = __builtin_amdgcn_mfma_f32_16x16x32_bf16(aa0, bo, oacc[0], 0, 0, 0);
        oacc[1] = __builtin_amdgcn_mfma_f32_16x16x32_bf16(aa1, bo, oacc[1], 0, 0, 0);
      }
    }
  }
  {
    float bj = outb[w*16 + fcol];
    #pragma unroll
    for (int rt = 0; rt < 2; ++rt)
      #pragma unroll
      for (int j = 0; j < 4; ++j) {
        int n = n0 + rt*16 + g4 + j;
        out[((size_t)b*N_ + n)*64 + w*16 + fcol] = oacc[rt][j] + bj;
      }
  }
}

extern "C" void kernel_launch(void* const* d_in, const int* in_sizes, int n_in,
                              void* d_out, int out_size, void* d_ws, size_t ws_size,
                              hipStream_t stream) {
  const float* query  = (const float*)d_in[0];
  const float* key    = (const float*)d_in[1];
  const float* value  = (const float*)d_in[2];
  const float* coords = (const float*)d_in[3];
  const void*  mask   = d_in[4];
  const float* wrpe   = (const float*)d_in[5];
  const float* omR    = (const float*)d_in[6];
  const float* omA    = (const float*)d_in[7];
  const float* proj   = (const float*)d_in[8];
  const float* outw   = (const float*)d_in[9];
  const float* outb   = (const float*)d_in[10];
  float* W = (float*)d_ws;
  float* out = (float*)d_out;

  hipMemsetAsync(W + ZERO_BEG, 0, (size_t)(ZERO_END - ZERO_BEG)*sizeof(float), stream);
  hipLaunchKernelGGL(k_consts,   dim3(1),        dim3(256), 0, stream, wrpe, outw,
                     (const unsigned int*)mask, W);
  hipLaunchKernelGGL(k_pass1,    dim3(32*NCH),   dim3(256), 0, stream, key, value, coords, mask,
                     omR, omA, proj, W);
  hipLaunchKernelGGL(k_mkred,    dim3(1),        dim3(64),  0, stream, W);
  hipLaunchKernelGGL(k_finalize, dim3(32),       dim3(256), 0, stream, W);
  hipLaunchKernelGGL(k_pass2,    dim3(1024),     dim3(256), 0, stream, query, coords, omR, omA,
                     proj, outb, W, out);
}